// Round 9
// baseline (191.035 us; speedup 1.0000x reference)
//
#include <hip/hip_runtime.h>
#include <math.h>

#define HW     76800
#define HW4    19200
#define NCH    86
#define OCH    89
#define NB     4
#define VOX    32768
#define NBLKV  75         // f4 blocks per batch (1024 px each)
#define THRESHF 0.7f
#define BIGF   1e30f

typedef float f4 __attribute__((ext_vector_type(4)));

// ws float layout:
// [64..207]   M: (b*3 + k)*12 row-major 3x4 [R|t]     (written by k_minmax bx==0)
// [256..279]  minmax keys (uint32): b*6 + c           (init by k_votes_zero blk(0,0))
// [512..5312) vote partials: (b*75+bx)*16 + i, i<14   (k_votes_zero)
// [32768..]   occ_tmp: [b][vox][64] voxel-major scratch (33.5 MB)

__device__ __forceinline__ float sigmoidf_(float x) {
    if (x >= 0.f) { return 1.f / (1.f + expf(-x)); }
    float e = expf(x); return e / (1.f + e);
}
__device__ __forceinline__ unsigned fkey(float f) {
    unsigned u = __float_as_uint(f);
    return (u & 0x80000000u) ? ~u : (u | 0x80000000u);
}
__device__ __forceinline__ float funkey(unsigned k) {
    unsigned u = (k & 0x80000000u) ? (k ^ 0x80000000u) : ~k;
    return __uint_as_float(u);
}
__device__ __forceinline__ int vox1(float q) {
    int v = (int)floorf(q * 32.f);
    return v < 0 ? 0 : (v > 31 ? 31 : v);
}

// votes (f4, per-block partials) + zero occ_tmp + init minmax keys.
__global__ __launch_bounds__(256) void k_votes_zero(const f4* __restrict__ in4,
                                                    float* __restrict__ ws,
                                                    f4* __restrict__ zp, unsigned n4) {
    const int b = blockIdx.y, bx = blockIdx.x;
    const int tid = threadIdx.x;
    {   // zero slice of scratch
        unsigned gid = ((unsigned)(b * NBLKV + bx)) * 256u + tid;
        f4 z = {0.f, 0.f, 0.f, 0.f};
        for (unsigned i = gid; i < n4; i += NB * NBLKV * 256u)
            __builtin_nontemporal_store(z, &zp[i]);
    }
    if (b == 0 && bx == 0 && tid < 24) {
        unsigned* keys = (unsigned*)(ws + 256);
        keys[tid] = ((tid % 6) < 3) ? fkey(BIGF) : fkey(-BIGF);
    }
    const size_t ib = (size_t)b * NCH * HW4 + bx * 256 + tid;
    f4 mv = in4[ib + (size_t)3 * HW4];
    f4 c0 = in4[ib + (size_t)20 * HW4];
    f4 c1 = in4[ib + (size_t)21 * HW4];
    f4 L[12];
#pragma unroll
    for (int i = 0; i < 12; i++) L[i] = in4[ib + (size_t)(4 + i) * HW4];
    float acc[14];
#pragma unroll
    for (int i = 0; i < 14; i++) acc[i] = 0.f;
#pragma unroll
    for (int k = 0; k < 4; k++) {
        float m  = sigmoidf_(mv[k]);
        float s0 = sigmoidf_(c0[k]) * m;
        float s1 = sigmoidf_(c1[k]) * m;
        float w0 = m * s0, w1 = m * s1;
        acc[0] += s0; acc[7] += s1;
#pragma unroll
        for (int c = 0; c < 3; c++) {
            acc[1 + c]  += L[c][k]     * w0;
            acc[8 + c]  += L[3 + c][k] * w1;
            acc[4 + c]  += L[6 + c][k] * w0;
            acc[11 + c] += L[9 + c][k] * w1;
        }
    }
    __shared__ float red[4][14];
    int lane = tid & 63, wid = tid >> 6;
#pragma unroll
    for (int i = 0; i < 14; i++) {
        float v = acc[i];
        for (int off = 32; off > 0; off >>= 1) v += __shfl_down(v, off, 64);
        if (lane == 0) red[wid][i] = v;
    }
    __syncthreads();
    if (tid < 14)
        ws[512 + (b * NBLKV + bx) * 16 + tid] =
            red[0][tid] + red[1][tid] + red[2][tid] + red[3][tid];
}

// build M (redundant per block, from partials) + per-pixel minmax (f4).
__global__ __launch_bounds__(256) void k_minmax(const f4* __restrict__ in4,
                                                float* __restrict__ ws) {
    __shared__ float vsh[14];
    __shared__ float Msh[36];
    const int b = blockIdx.y, bx = blockIdx.x, tid = threadIdx.x;
    if (tid < 14) {
        const float* part = ws + 512 + (size_t)b * NBLKV * 16 + tid;
        float s = 0.f;
#pragma unroll 5
        for (int blk = 0; blk < NBLKV; blk++) s += part[blk * 16];
        vsh[tid] = s;
    }
    __syncthreads();
    if (tid < 3) {
        int k = tid;
        float lp0 = 0, lp1 = 0, lp2 = 0, rp0 = 0, rp1 = 0, rp2 = 0;
        if (k > 0) {
            const float* v = vsh + (k - 1) * 7;
            float d = v[0] + 1e-5f;
            lp0 = v[1] / d; lp1 = v[2] / d; lp2 = v[3] / d;
            rp0 = v[4] / d; rp1 = v[5] / d; rp2 = v[6] / d;
        }
        float rx = -rp0, ry = -rp1, rz = -rp2;
        float ang = sqrtf(rx * rx + ry * ry + rz * rz) + 1e-8f;
        float ax = rx / ang, ay = ry / ang, az = rz / ang;
        float K[3][3] = {{0.f, -az, ay}, {az, 0.f, -ax}, {-ay, ax, 0.f}};
        float c = cosf(ang), s = sinf(ang);
        float K2[3][3], Rm[3][3];
#pragma unroll
        for (int i = 0; i < 3; i++)
#pragma unroll
            for (int j = 0; j < 3; j++)
                K2[i][j] = K[i][0] * K[0][j] + K[i][1] * K[1][j] + K[i][2] * K[2][j];
#pragma unroll
        for (int i = 0; i < 3; i++)
#pragma unroll
            for (int j = 0; j < 3; j++)
                Rm[i][j] = (i == j ? 1.f : 0.f) + s * K[i][j] + (1.f - c) * K2[i][j];
#pragma unroll
        for (int i = 0; i < 3; i++) {
            float tt = (i == 0 ? lp0 : (i == 1 ? lp1 : lp2));
            float tr = tt - (Rm[i][0] * lp0 + Rm[i][1] * lp1 + Rm[i][2] * lp2);
            Msh[k * 12 + i * 4 + 0] = Rm[i][0];
            Msh[k * 12 + i * 4 + 1] = Rm[i][1];
            Msh[k * 12 + i * 4 + 2] = Rm[i][2];
            Msh[k * 12 + i * 4 + 3] = tr;
            if (bx == 0) {
                float* M = ws + 64 + (b * 3 + k) * 12;
                M[i * 4 + 0] = Rm[i][0]; M[i * 4 + 1] = Rm[i][1];
                M[i * 4 + 2] = Rm[i][2]; M[i * 4 + 3] = tr;
            }
        }
    }
    __syncthreads();

    const size_t ib = (size_t)b * NCH * HW4 + bx * 256 + tid;
    f4 n0 = in4[ib], n1 = in4[ib + HW4], n2 = in4[ib + 2 * HW4];
    f4 mv = in4[ib + 3 * HW4];
    f4 g0 = in4[ib + 16 * HW4], g1 = in4[ib + 17 * HW4];
    f4 g2 = in4[ib + 18 * HW4], g3 = in4[ib + 19 * HW4];
    float mn[3] = {BIGF, BIGF, BIGF}, mx[3] = {-BIGF, -BIGF, -BIGF};
#pragma unroll
    for (int k = 0; k < 4; k++) {
        float m = sigmoidf_(mv[k]);
        if (!(m > THRESHF)) continue;
        int am = 0; float bb = g0[k];
        if (g1[k] > bb) { bb = g1[k]; am = 1; }
        if (g2[k] > bb) { bb = g2[k]; am = 2; }
        if (g3[k] > bb) { bb = g3[k]; am = 3; }
        float px = 0.f, py = 0.f, pz = 0.f;
        if (am > 0) {
            const float* Mk = Msh + (am - 1) * 12;
            float a = n0[k], bq = n1[k], cq = n2[k];
            px = Mk[0] * a + Mk[1] * bq + Mk[2]  * cq + Mk[3];
            py = Mk[4] * a + Mk[5] * bq + Mk[6]  * cq + Mk[7];
            pz = Mk[8] * a + Mk[9] * bq + Mk[10] * cq + Mk[11];
        }
        mn[0] = fminf(mn[0], px); mn[1] = fminf(mn[1], py); mn[2] = fminf(mn[2], pz);
        mx[0] = fmaxf(mx[0], px); mx[1] = fmaxf(mx[1], py); mx[2] = fmaxf(mx[2], pz);
    }
    __shared__ float rmn[4][3], rmx[4][3];
    int lane = tid & 63, wid = tid >> 6;
#pragma unroll
    for (int i = 0; i < 3; i++) {
        float v = mn[i];
        for (int off = 32; off > 0; off >>= 1) v = fminf(v, __shfl_down(v, off, 64));
        if (lane == 0) rmn[wid][i] = v;
        float u = mx[i];
        for (int off = 32; off > 0; off >>= 1) u = fmaxf(u, __shfl_down(u, off, 64));
        if (lane == 0) rmx[wid][i] = u;
    }
    __syncthreads();
    unsigned* keys = (unsigned*)(ws + 256);
    if (tid < 3) {
        float v = fminf(fminf(rmn[0][tid], rmn[1][tid]), fminf(rmn[2][tid], rmn[3][tid]));
        atomicMin(&keys[b * 6 + tid], fkey(v));
    } else if (tid < 6) {
        int i = tid - 3;
        float v = fmaxf(fmaxf(rmx[0][i], rmx[1][i]), fmaxf(rmx[2][i], rmx[3][i]));
        atomicMax(&keys[b * 6 + 3 + i], fkey(v));
    }
}

// ALL out_cat copies + pn + dedup'd voxel scatter. 256 px/block, single
// 64-channel pass (R6 structure — R8's 2-pass split regressed). Loads are
// SPLIT from stores: all 22 f4 loads issue into registers first (deep MLP);
// per-pixel compute overlaps the latency.
template<bool VOXMAJOR>
__global__ __launch_bounds__(256) void k_scatter(const f4* __restrict__ in4,
                                                 f4* __restrict__ out4,
                                                 float* __restrict__ dst,
                                                 const float* __restrict__ ws) {
    __shared__ float tile[64][257];
    const int b = blockIdx.y, blk = blockIdx.x;
    const int tid = threadIdx.x, lane = tid & 63, w = tid >> 6;
    const size_t ib4 = (size_t)b * NCH * HW4 + (size_t)blk * 64;
    const size_t ob4 = (size_t)b * OCH * HW4 + (size_t)blk * 64;
    const int w16 = w * 16;

    // ---- issue ALL loads first (deep MLP) ----
    f4 va[6];                       // phase A: ch {w, w+4, ...} < 22 (regular: L1-hot)
#pragma unroll
    for (int i = 0; i < 6; i++) {
        int c = w + 4 * i;
        if (c < 22) va[i] = in4[ib4 + (size_t)c * HW4 + lane];
    }
    f4 vb[16];                      // feat: ch 22+w16 .. 22+w16+15 (NT: no reuse)
#pragma unroll
    for (int i = 0; i < 16; i++)
        vb[i] = __builtin_nontemporal_load(&in4[ib4 + (size_t)(22 + w16 + i) * HW4 + lane]);

    // ---- per-pixel info (px = blk*256 + tid), scalar reads (L1/L2-hot) ----
    const unsigned* keys = (const unsigned*)(ws + 256);
    float l0 = funkey(keys[b * 6 + 0]), l1 = funkey(keys[b * 6 + 1]), l2 = funkey(keys[b * 6 + 2]);
    float u0 = funkey(keys[b * 6 + 3]), u1 = funkey(keys[b * 6 + 4]), u2 = funkey(keys[b * 6 + 5]);
    float scale = fmaxf(u0 - l0, fmaxf(u1 - l1, u2 - l2));
    float safe = (scale == 0.f) ? 1.f : scale;
    bool flag = scale != 0.f;
    float z0 = flag ? (0.f - l0) / safe : 0.f;
    float z1 = flag ? (0.f - l1) / safe : 0.f;
    float z2 = flag ? (0.f - l2) / safe : 0.f;
    const int fl0 = vox1(z0) * 1024 + vox1(z1) * 32 + vox1(z2);

    const float* ibs = (const float*)in4 + (size_t)b * NCH * HW + blk * 256 + tid;
    float* obs = (float*)out4 + (size_t)b * OCH * HW + blk * 256 + tid;
    float n0 = ibs[0], n1 = ibs[(size_t)HW], n2 = ibs[(size_t)2 * HW];
    float mvv = ibs[(size_t)3 * HW];
    float g0 = ibs[(size_t)16 * HW], g1 = ibs[(size_t)17 * HW];
    float g2 = ibs[(size_t)18 * HW], g3 = ibs[(size_t)19 * HW];
    float m = sigmoidf_(mvv);
    bool masked = m > THRESHF;
    int am = 0;
    { float bb = g0;
      if (g1 > bb) { bb = g1; am = 1; }
      if (g2 > bb) { bb = g2; am = 2; }
      if (g3 > bb) { bb = g3; am = 3; } }
    float px = 0.f, py = 0.f, pz = 0.f;
    if (am > 0) {
        const float* Mk = ws + 64 + b * 36 + (am - 1) * 12;
        px = Mk[0] * n0 + Mk[1] * n1 + Mk[2]  * n2 + Mk[3];
        py = Mk[4] * n0 + Mk[5] * n1 + Mk[6]  * n2 + Mk[7];
        pz = Mk[8] * n0 + Mk[9] * n1 + Mk[10] * n2 + Mk[11];
    }
    float qx, qy, qz;
    if (flag) { qx = (px - l0) / safe; qy = (py - l1) / safe; qz = (pz - l2) / safe; }
    else      { qx = px; qy = py; qz = pz; }
    float ox = masked ? qx : 0.f, oy = masked ? qy : 0.f, oz = masked ? qz : 0.f;
    __builtin_nontemporal_store(ox, &obs[(size_t)86 * HW]);
    __builtin_nontemporal_store(oy, &obs[(size_t)87 * HW]);
    __builtin_nontemporal_store(oz, &obs[(size_t)88 * HW]);
    int flat = masked ? ((am != 0) ? (vox1(ox) * 1024 + vox1(oy) * 32 + vox1(oz)) : fl0)
                      : -1;
    const unsigned long long gm_all = __ballot(masked);

    // ---- stores (loads long in flight by now) ----
#pragma unroll
    for (int i = 0; i < 6; i++) {
        int c = w + 4 * i;
        if (c < 22) __builtin_nontemporal_store(va[i], &out4[ob4 + (size_t)c * HW4 + lane]);
    }
#pragma unroll
    for (int i = 0; i < 16; i++) {
        int c = w16 + i;
        __builtin_nontemporal_store(vb[i], &out4[ob4 + (size_t)(22 + c) * HW4 + lane]);
        tile[c][4 * lane + 0] = vb[i][0]; tile[c][4 * lane + 1] = vb[i][1];
        tile[c][4 * lane + 2] = vb[i][2]; tile[c][4 * lane + 3] = vb[i][3];
    }
    __syncthreads();   // tile ready

    // ---- dedup'd drain: one 256B wave-atomic per DISTINCT voxel ----
    unsigned long long gm = gm_all;
    while (gm) {
        int i0 = __ffsll(gm) - 1;
        int fl = __shfl(flat, i0, 64);
        unsigned long long match = __ballot(flat == fl) & gm;
        gm &= ~match;
        float s = 0.f;
        unsigned long long mm = match;
        while (mm) {
            int j = __ffsll(mm) - 1; mm &= mm - 1;
            s += tile[lane][w * 64 + j];
        }
        if (VOXMAJOR)
            atomicAdd(&dst[(((size_t)b * VOX + fl) << 6) + lane], s);
        else
            atomicAdd(&dst[(((size_t)(b * 64 + lane)) << 15) + fl], s);
    }
}

// tmp[b][vox][64] -> occ[b][64][vox]. 256-voxel tiles: 1KB contiguous per
// channel write (4x better locality than 64-voxel version).
__global__ __launch_bounds__(256) void k_transpose(const float* __restrict__ tmp,
                                                   float* __restrict__ occ) {
    __shared__ float ld[64][257];
    const int b = blockIdx.y;
    const int vox0 = blockIdx.x * 256;
    const int t = threadIdx.x;
    const int v = t & 63, g = t >> 6;          // g: 16 channels each
#pragma unroll
    for (int q = 0; q < 4; q++) {
        int vox = q * 64 + v;
        const float* src = tmp + (((size_t)b * VOX + vox0 + vox) << 6) + g * 16;
#pragma unroll
        for (int i = 0; i < 4; i++) {
            f4 x = *(const f4*)(src + 4 * i);
            ld[g * 16 + 4 * i + 0][vox] = x[0];
            ld[g * 16 + 4 * i + 1][vox] = x[1];
            ld[g * 16 + 4 * i + 2][vox] = x[2];
            ld[g * 16 + 4 * i + 3][vox] = x[3];
        }
    }
    __syncthreads();
    const int f = t >> 2, sub = t & 3;         // 4 threads per channel
    float* dstp = occ + (((size_t)(b * 64 + f)) << 15) + vox0;
#pragma unroll
    for (int i = 0; i < 16; i++) {
        int mq = sub * 16 + i;                  // f4 index 0..63
        f4 x;
        x[0] = ld[f][4 * mq + 0]; x[1] = ld[f][4 * mq + 1];
        x[2] = ld[f][4 * mq + 2]; x[3] = ld[f][4 * mq + 3];
        __builtin_nontemporal_store(x, (f4*)(dstp + 4 * mq));
    }
}

extern "C" void kernel_launch(void* const* d_in, const int* in_sizes, int n_in,
                              void* d_out, int out_size, void* d_ws, size_t ws_size,
                              hipStream_t stream) {
    const f4* in4 = (const f4*)d_in[0];
    float* out = (float*)d_out;
    float* ws = (float*)d_ws;
    float* occ = out + (size_t)NB * OCH * HW;
    float* tmp = ws + 32768;
    const size_t tmp_bytes = (size_t)NB * VOX * 64 * sizeof(float);
    const bool voxmajor = ws_size >= 32768 * sizeof(float) + tmp_bytes;
    const unsigned n4 = (unsigned)(tmp_bytes / 16);

    dim3 g75(NBLKV, NB);
    if (voxmajor) k_votes_zero<<<g75, 256, 0, stream>>>(in4, ws, (f4*)tmp, n4);
    else          k_votes_zero<<<g75, 256, 0, stream>>>(in4, ws, (f4*)occ, n4);
    k_minmax<<<g75, 256, 0, stream>>>(in4, ws);
    dim3 gs(300, NB);
    if (voxmajor) {
        k_scatter<true><<<gs, 256, 0, stream>>>(in4, (f4*)out, tmp, ws);
        dim3 gt(VOX / 256, NB);
        k_transpose<<<gt, 256, 0, stream>>>(tmp, occ);
    } else {
        k_scatter<false><<<gs, 256, 0, stream>>>(in4, (f4*)out, occ, ws);
    }
}

// Round 10
// 172.233 us; speedup vs baseline: 1.1092x; 1.1092x over previous
//
#include <hip/hip_runtime.h>
#include <math.h>

#define HW     76800
#define HW4    19200
#define NCH    86
#define OCH    89
#define NB     4
#define VOX    32768
#define NBLKV  75         // f4 blocks per batch (1024 px each)
#define THRESHF 0.7f
#define BIGF   1e30f

typedef float f4 __attribute__((ext_vector_type(4)));

// ws float layout:
// [64..207]   M: (b*3 + k)*12 row-major 3x4 [R|t]     (written by k_minmax bx==0)
// [256..279]  minmax keys (uint32): b*6 + c           (init by k_votes_zero blk(0,0))
// [512..5312) vote partials: (b*75+bx)*16 + i, i<14   (k_votes_zero)
// [32768..]   occ_tmp: [b][vox][64] voxel-major scratch (33.5 MB)

__device__ __forceinline__ float sigmoidf_(float x) {
    if (x >= 0.f) { return 1.f / (1.f + expf(-x)); }
    float e = expf(x); return e / (1.f + e);
}
__device__ __forceinline__ unsigned fkey(float f) {
    unsigned u = __float_as_uint(f);
    return (u & 0x80000000u) ? ~u : (u | 0x80000000u);
}
__device__ __forceinline__ float funkey(unsigned k) {
    unsigned u = (k & 0x80000000u) ? (k ^ 0x80000000u) : ~k;
    return __uint_as_float(u);
}
__device__ __forceinline__ int vox1(float q) {
    int v = (int)floorf(q * 32.f);
    return v < 0 ? 0 : (v > 31 ? 31 : v);
}

// votes (f4, per-block partials) + zero occ_tmp + init minmax keys.
__global__ __launch_bounds__(256) void k_votes_zero(const f4* __restrict__ in4,
                                                    float* __restrict__ ws,
                                                    f4* __restrict__ zp, unsigned n4) {
    const int b = blockIdx.y, bx = blockIdx.x;
    const int tid = threadIdx.x;
    {   // zero slice of scratch
        unsigned gid = ((unsigned)(b * NBLKV + bx)) * 256u + tid;
        f4 z = {0.f, 0.f, 0.f, 0.f};
        for (unsigned i = gid; i < n4; i += NB * NBLKV * 256u)
            __builtin_nontemporal_store(z, &zp[i]);
    }
    if (b == 0 && bx == 0 && tid < 24) {
        unsigned* keys = (unsigned*)(ws + 256);
        keys[tid] = ((tid % 6) < 3) ? fkey(BIGF) : fkey(-BIGF);
    }
    const size_t ib = (size_t)b * NCH * HW4 + bx * 256 + tid;
    f4 mv = in4[ib + (size_t)3 * HW4];
    f4 c0 = in4[ib + (size_t)20 * HW4];
    f4 c1 = in4[ib + (size_t)21 * HW4];
    f4 L[12];
#pragma unroll
    for (int i = 0; i < 12; i++) L[i] = in4[ib + (size_t)(4 + i) * HW4];
    float acc[14];
#pragma unroll
    for (int i = 0; i < 14; i++) acc[i] = 0.f;
#pragma unroll
    for (int k = 0; k < 4; k++) {
        float m  = sigmoidf_(mv[k]);
        float s0 = sigmoidf_(c0[k]) * m;
        float s1 = sigmoidf_(c1[k]) * m;
        float w0 = m * s0, w1 = m * s1;
        acc[0] += s0; acc[7] += s1;
#pragma unroll
        for (int c = 0; c < 3; c++) {
            acc[1 + c]  += L[c][k]     * w0;
            acc[8 + c]  += L[3 + c][k] * w1;
            acc[4 + c]  += L[6 + c][k] * w0;
            acc[11 + c] += L[9 + c][k] * w1;
        }
    }
    __shared__ float red[4][14];
    int lane = tid & 63, wid = tid >> 6;
#pragma unroll
    for (int i = 0; i < 14; i++) {
        float v = acc[i];
        for (int off = 32; off > 0; off >>= 1) v += __shfl_down(v, off, 64);
        if (lane == 0) red[wid][i] = v;
    }
    __syncthreads();
    if (tid < 14)
        ws[512 + (b * NBLKV + bx) * 16 + tid] =
            red[0][tid] + red[1][tid] + red[2][tid] + red[3][tid];
}

// build M (redundant per block, from partials) + per-pixel minmax (f4).
__global__ __launch_bounds__(256) void k_minmax(const f4* __restrict__ in4,
                                                float* __restrict__ ws) {
    __shared__ float vsh[14];
    __shared__ float Msh[36];
    const int b = blockIdx.y, bx = blockIdx.x, tid = threadIdx.x;
    if (tid < 14) {
        const float* part = ws + 512 + (size_t)b * NBLKV * 16 + tid;
        float s = 0.f;
#pragma unroll 5
        for (int blk = 0; blk < NBLKV; blk++) s += part[blk * 16];
        vsh[tid] = s;
    }
    __syncthreads();
    if (tid < 3) {
        int k = tid;
        float lp0 = 0, lp1 = 0, lp2 = 0, rp0 = 0, rp1 = 0, rp2 = 0;
        if (k > 0) {
            const float* v = vsh + (k - 1) * 7;
            float d = v[0] + 1e-5f;
            lp0 = v[1] / d; lp1 = v[2] / d; lp2 = v[3] / d;
            rp0 = v[4] / d; rp1 = v[5] / d; rp2 = v[6] / d;
        }
        float rx = -rp0, ry = -rp1, rz = -rp2;
        float ang = sqrtf(rx * rx + ry * ry + rz * rz) + 1e-8f;
        float ax = rx / ang, ay = ry / ang, az = rz / ang;
        float K[3][3] = {{0.f, -az, ay}, {az, 0.f, -ax}, {-ay, ax, 0.f}};
        float c = cosf(ang), s = sinf(ang);
        float K2[3][3], Rm[3][3];
#pragma unroll
        for (int i = 0; i < 3; i++)
#pragma unroll
            for (int j = 0; j < 3; j++)
                K2[i][j] = K[i][0] * K[0][j] + K[i][1] * K[1][j] + K[i][2] * K[2][j];
#pragma unroll
        for (int i = 0; i < 3; i++)
#pragma unroll
            for (int j = 0; j < 3; j++)
                Rm[i][j] = (i == j ? 1.f : 0.f) + s * K[i][j] + (1.f - c) * K2[i][j];
#pragma unroll
        for (int i = 0; i < 3; i++) {
            float tt = (i == 0 ? lp0 : (i == 1 ? lp1 : lp2));
            float tr = tt - (Rm[i][0] * lp0 + Rm[i][1] * lp1 + Rm[i][2] * lp2);
            Msh[k * 12 + i * 4 + 0] = Rm[i][0];
            Msh[k * 12 + i * 4 + 1] = Rm[i][1];
            Msh[k * 12 + i * 4 + 2] = Rm[i][2];
            Msh[k * 12 + i * 4 + 3] = tr;
            if (bx == 0) {
                float* M = ws + 64 + (b * 3 + k) * 12;
                M[i * 4 + 0] = Rm[i][0]; M[i * 4 + 1] = Rm[i][1];
                M[i * 4 + 2] = Rm[i][2]; M[i * 4 + 3] = tr;
            }
        }
    }
    __syncthreads();

    const size_t ib = (size_t)b * NCH * HW4 + bx * 256 + tid;
    f4 n0 = in4[ib], n1 = in4[ib + HW4], n2 = in4[ib + 2 * HW4];
    f4 mv = in4[ib + 3 * HW4];
    f4 g0 = in4[ib + 16 * HW4], g1 = in4[ib + 17 * HW4];
    f4 g2 = in4[ib + 18 * HW4], g3 = in4[ib + 19 * HW4];
    float mn[3] = {BIGF, BIGF, BIGF}, mx[3] = {-BIGF, -BIGF, -BIGF};
#pragma unroll
    for (int k = 0; k < 4; k++) {
        float m = sigmoidf_(mv[k]);
        if (!(m > THRESHF)) continue;
        int am = 0; float bb = g0[k];
        if (g1[k] > bb) { bb = g1[k]; am = 1; }
        if (g2[k] > bb) { bb = g2[k]; am = 2; }
        if (g3[k] > bb) { bb = g3[k]; am = 3; }
        float px = 0.f, py = 0.f, pz = 0.f;
        if (am > 0) {
            const float* Mk = Msh + (am - 1) * 12;
            float a = n0[k], bq = n1[k], cq = n2[k];
            px = Mk[0] * a + Mk[1] * bq + Mk[2]  * cq + Mk[3];
            py = Mk[4] * a + Mk[5] * bq + Mk[6]  * cq + Mk[7];
            pz = Mk[8] * a + Mk[9] * bq + Mk[10] * cq + Mk[11];
        }
        mn[0] = fminf(mn[0], px); mn[1] = fminf(mn[1], py); mn[2] = fminf(mn[2], pz);
        mx[0] = fmaxf(mx[0], px); mx[1] = fmaxf(mx[1], py); mx[2] = fmaxf(mx[2], pz);
    }
    __shared__ float rmn[4][3], rmx[4][3];
    int lane = tid & 63, wid = tid >> 6;
#pragma unroll
    for (int i = 0; i < 3; i++) {
        float v = mn[i];
        for (int off = 32; off > 0; off >>= 1) v = fminf(v, __shfl_down(v, off, 64));
        if (lane == 0) rmn[wid][i] = v;
        float u = mx[i];
        for (int off = 32; off > 0; off >>= 1) u = fmaxf(u, __shfl_down(u, off, 64));
        if (lane == 0) rmx[wid][i] = u;
    }
    __syncthreads();
    unsigned* keys = (unsigned*)(ws + 256);
    if (tid < 3) {
        float v = fminf(fminf(rmn[0][tid], rmn[1][tid]), fminf(rmn[2][tid], rmn[3][tid]));
        atomicMin(&keys[b * 6 + tid], fkey(v));
    } else if (tid < 6) {
        int i = tid - 3;
        float v = fmaxf(fmaxf(rmx[0][i], rmx[1][i]), fmaxf(rmx[2][i], rmx[3][i]));
        atomicMax(&keys[b * 6 + 3 + i], fkey(v));
    }
}

// ALL out_cat copies + pn + dedup'd voxel scatter. 256 px/block. NO LDS:
// the drain reads channel values straight from global (L1/L2/L3-hot — each
// lane's 64-px channel row is 4 cache lines). Removes the 66KB tile that
// capped occupancy at 2 blocks/CU, and both __syncthreads.
template<bool VOXMAJOR>
__global__ __launch_bounds__(256) void k_scatter(const f4* __restrict__ in4,
                                                 f4* __restrict__ out4,
                                                 float* __restrict__ dst,
                                                 const float* __restrict__ ws) {
    const int b = blockIdx.y, blk = blockIdx.x;
    const int tid = threadIdx.x, lane = tid & 63, w = tid >> 6;
    const size_t ib4 = (size_t)b * NCH * HW4 + (size_t)blk * 64;
    const size_t ob4 = (size_t)b * OCH * HW4 + (size_t)blk * 64;

    // prep decode (uniform per thread)
    const unsigned* keys = (const unsigned*)(ws + 256);
    float l0 = funkey(keys[b * 6 + 0]), l1 = funkey(keys[b * 6 + 1]), l2 = funkey(keys[b * 6 + 2]);
    float u0 = funkey(keys[b * 6 + 3]), u1 = funkey(keys[b * 6 + 4]), u2 = funkey(keys[b * 6 + 5]);
    float scale = fmaxf(u0 - l0, fmaxf(u1 - l1, u2 - l2));
    float safe = (scale == 0.f) ? 1.f : scale;
    bool flag = scale != 0.f;
    float z0 = flag ? (0.f - l0) / safe : 0.f;
    float z1 = flag ? (0.f - l1) / safe : 0.f;
    float z2 = flag ? (0.f - l2) / safe : 0.f;
    const int fl0 = vox1(z0) * 1024 + vox1(z1) * 32 + vox1(z2);

    // per-pixel info (px = blk*256 + tid), scalar reads (L2/L3-hot)
    const float* ibs = (const float*)in4 + (size_t)b * NCH * HW + blk * 256 + tid;
    float* obs = (float*)out4 + (size_t)b * OCH * HW + blk * 256 + tid;
    float n0 = ibs[0], n1 = ibs[(size_t)HW], n2 = ibs[(size_t)2 * HW];
    float mvv = ibs[(size_t)3 * HW];
    float g0 = ibs[(size_t)16 * HW], g1 = ibs[(size_t)17 * HW];
    float g2 = ibs[(size_t)18 * HW], g3 = ibs[(size_t)19 * HW];
    float m = sigmoidf_(mvv);
    bool masked = m > THRESHF;
    int am = 0;
    { float bb = g0;
      if (g1 > bb) { bb = g1; am = 1; }
      if (g2 > bb) { bb = g2; am = 2; }
      if (g3 > bb) { bb = g3; am = 3; } }
    float px = 0.f, py = 0.f, pz = 0.f;
    if (am > 0) {
        const float* Mk = ws + 64 + b * 36 + (am - 1) * 12;
        px = Mk[0] * n0 + Mk[1] * n1 + Mk[2]  * n2 + Mk[3];
        py = Mk[4] * n0 + Mk[5] * n1 + Mk[6]  * n2 + Mk[7];
        pz = Mk[8] * n0 + Mk[9] * n1 + Mk[10] * n2 + Mk[11];
    }
    float qx, qy, qz;
    if (flag) { qx = (px - l0) / safe; qy = (py - l1) / safe; qz = (pz - l2) / safe; }
    else      { qx = px; qy = py; qz = pz; }
    float ox = masked ? qx : 0.f, oy = masked ? qy : 0.f, oz = masked ? qz : 0.f;
    __builtin_nontemporal_store(ox, &obs[(size_t)86 * HW]);
    __builtin_nontemporal_store(oy, &obs[(size_t)87 * HW]);
    __builtin_nontemporal_store(oz, &obs[(size_t)88 * HW]);
    int flat = masked ? ((am != 0) ? (vox1(ox) * 1024 + vox1(oy) * 32 + vox1(oz)) : fl0)
                      : -1;
    unsigned long long gm = __ballot(masked);

    // copies: ch 0..21 (wave-split) + feat 22..85 (wave w: 16 channels).
    // Regular loads (keep L2-hot for the drain gather); NT stores.
    for (int c = w; c < 22; c += 4) {
        f4 v = in4[ib4 + (size_t)c * HW4 + lane];
        __builtin_nontemporal_store(v, &out4[ob4 + (size_t)c * HW4 + lane]);
    }
#pragma unroll 4
    for (int i = 0; i < 16; i++) {
        int c = 22 + w * 16 + i;
        f4 v = in4[ib4 + (size_t)c * HW4 + lane];
        __builtin_nontemporal_store(v, &out4[ob4 + (size_t)c * HW4 + lane]);
    }

    // dedup'd drain: one 256B wave-atomic per DISTINCT voxel; channel values
    // gathered from global (lane = channel; row base per lane, uniform px).
    const float* gsrc = (const float*)in4 + (size_t)b * NCH * HW
                      + (size_t)(22 + lane) * HW + blk * 256 + w * 64;
    while (gm) {
        int i0 = __ffsll(gm) - 1;
        int fl = __shfl(flat, i0, 64);
        unsigned long long match = __ballot(flat == fl) & gm;
        gm &= ~match;
        float s = 0.f;
        unsigned long long mm = match;
        while (mm) {
            int j = __ffsll(mm) - 1; mm &= mm - 1;
            s += gsrc[j];
        }
        if (VOXMAJOR)
            atomicAdd(&dst[(((size_t)b * VOX + fl) << 6) + lane], s);
        else
            atomicAdd(&dst[(((size_t)(b * 64 + lane)) << 15) + fl], s);
    }
}

// tmp[b][vox][64] -> occ[b][64][vox], 64-voxel tiles (16.6KB LDS, 2048 blocks
// — the R9 256-voxel/66KB version dropped to 1 block/CU and regressed).
__global__ __launch_bounds__(256) void k_transpose(const float* __restrict__ tmp,
                                                   float* __restrict__ occ) {
    __shared__ float ld[64][65];
    const int b = blockIdx.y;
    const int vox0 = blockIdx.x * 64;
    const int t = threadIdx.x;
    const int v = t & 63, g = t >> 6;
    const float* src = tmp + (((size_t)b * VOX + vox0 + v) << 6) + g * 16;
#pragma unroll
    for (int i = 0; i < 4; i++) {
        f4 x = *(const f4*)(src + 4 * i);
        ld[g * 16 + 4 * i + 0][v] = x[0];
        ld[g * 16 + 4 * i + 1][v] = x[1];
        ld[g * 16 + 4 * i + 2][v] = x[2];
        ld[g * 16 + 4 * i + 3][v] = x[3];
    }
    __syncthreads();
    const int f = t >> 2;
    float* dstp = occ + (((size_t)(b * 64 + f)) << 15) + vox0;
#pragma unroll
    for (int i = 0; i < 4; i++) {
        int mq = (t & 3) * 4 + i;
        f4 x;
        x[0] = ld[f][4 * mq + 0]; x[1] = ld[f][4 * mq + 1];
        x[2] = ld[f][4 * mq + 2]; x[3] = ld[f][4 * mq + 3];
        __builtin_nontemporal_store(x, (f4*)(dstp + 4 * mq));
    }
}

extern "C" void kernel_launch(void* const* d_in, const int* in_sizes, int n_in,
                              void* d_out, int out_size, void* d_ws, size_t ws_size,
                              hipStream_t stream) {
    const f4* in4 = (const f4*)d_in[0];
    float* out = (float*)d_out;
    float* ws = (float*)d_ws;
    float* occ = out + (size_t)NB * OCH * HW;
    float* tmp = ws + 32768;
    const size_t tmp_bytes = (size_t)NB * VOX * 64 * sizeof(float);
    const bool voxmajor = ws_size >= 32768 * sizeof(float) + tmp_bytes;
    const unsigned n4 = (unsigned)(tmp_bytes / 16);

    dim3 g75(NBLKV, NB);
    if (voxmajor) k_votes_zero<<<g75, 256, 0, stream>>>(in4, ws, (f4*)tmp, n4);
    else          k_votes_zero<<<g75, 256, 0, stream>>>(in4, ws, (f4*)occ, n4);
    k_minmax<<<g75, 256, 0, stream>>>(in4, ws);
    dim3 gs(300, NB);
    if (voxmajor) {
        k_scatter<true><<<gs, 256, 0, stream>>>(in4, (f4*)out, tmp, ws);
        dim3 gt(VOX / 64, NB);
        k_transpose<<<gt, 256, 0, stream>>>(tmp, occ);
    } else {
        k_scatter<false><<<gs, 256, 0, stream>>>(in4, (f4*)out, occ, ws);
    }
}

// Round 11
// 103.363 us; speedup vs baseline: 1.8482x; 1.6663x over previous
//
#include <hip/hip_runtime.h>
#include <math.h>

#define HW     76800
#define HW4    19200
#define NCH    86
#define OCH    89
#define NB     4
#define VOX    32768
#define NBLKV  75         // f4 blocks per batch (1024 px each)
#define THRESHF 0.7f
#define BIGF   1e30f

typedef float f4 __attribute__((ext_vector_type(4)));

// ws float layout:
// [64..207]   M: (b*3 + k)*12 row-major 3x4 [R|t]     (written by k_minmax bx==0)
// [256..279]  minmax keys (uint32): b*6 + c           (init by k_votes_zero blk(0,0))
// [512..5312) vote partials: (b*75+bx)*16 + i, i<14   (k_votes_zero)
// [32768..]   occ_tmp: [b][vox][64] voxel-major scratch (33.5 MB)

__device__ __forceinline__ float sigmoidf_(float x) {
    if (x >= 0.f) { return 1.f / (1.f + expf(-x)); }
    float e = expf(x); return e / (1.f + e);
}
__device__ __forceinline__ unsigned fkey(float f) {
    unsigned u = __float_as_uint(f);
    return (u & 0x80000000u) ? ~u : (u | 0x80000000u);
}
__device__ __forceinline__ float funkey(unsigned k) {
    unsigned u = (k & 0x80000000u) ? (k ^ 0x80000000u) : ~k;
    return __uint_as_float(u);
}
__device__ __forceinline__ int vox1(float q) {
    int v = (int)floorf(q * 32.f);
    return v < 0 ? 0 : (v > 31 ? 31 : v);
}

// votes (f4, per-block partials) + zero occ_tmp + init minmax keys.
__global__ __launch_bounds__(256) void k_votes_zero(const f4* __restrict__ in4,
                                                    float* __restrict__ ws,
                                                    f4* __restrict__ zp, unsigned n4) {
    const int b = blockIdx.y, bx = blockIdx.x;
    const int tid = threadIdx.x;
    {   // zero slice of scratch (d_ws: NT stores are fast here)
        unsigned gid = ((unsigned)(b * NBLKV + bx)) * 256u + tid;
        f4 z = {0.f, 0.f, 0.f, 0.f};
        for (unsigned i = gid; i < n4; i += NB * NBLKV * 256u)
            __builtin_nontemporal_store(z, &zp[i]);
    }
    if (b == 0 && bx == 0 && tid < 24) {
        unsigned* keys = (unsigned*)(ws + 256);
        keys[tid] = ((tid % 6) < 3) ? fkey(BIGF) : fkey(-BIGF);
    }
    const size_t ib = (size_t)b * NCH * HW4 + bx * 256 + tid;
    f4 mv = in4[ib + (size_t)3 * HW4];
    f4 c0 = in4[ib + (size_t)20 * HW4];
    f4 c1 = in4[ib + (size_t)21 * HW4];
    f4 L[12];
#pragma unroll
    for (int i = 0; i < 12; i++) L[i] = in4[ib + (size_t)(4 + i) * HW4];
    float acc[14];
#pragma unroll
    for (int i = 0; i < 14; i++) acc[i] = 0.f;
#pragma unroll
    for (int k = 0; k < 4; k++) {
        float m  = sigmoidf_(mv[k]);
        float s0 = sigmoidf_(c0[k]) * m;
        float s1 = sigmoidf_(c1[k]) * m;
        float w0 = m * s0, w1 = m * s1;
        acc[0] += s0; acc[7] += s1;
#pragma unroll
        for (int c = 0; c < 3; c++) {
            acc[1 + c]  += L[c][k]     * w0;
            acc[8 + c]  += L[3 + c][k] * w1;
            acc[4 + c]  += L[6 + c][k] * w0;
            acc[11 + c] += L[9 + c][k] * w1;
        }
    }
    __shared__ float red[4][14];
    int lane = tid & 63, wid = tid >> 6;
#pragma unroll
    for (int i = 0; i < 14; i++) {
        float v = acc[i];
        for (int off = 32; off > 0; off >>= 1) v += __shfl_down(v, off, 64);
        if (lane == 0) red[wid][i] = v;
    }
    __syncthreads();
    if (tid < 14)
        ws[512 + (b * NBLKV + bx) * 16 + tid] =
            red[0][tid] + red[1][tid] + red[2][tid] + red[3][tid];
}

// build M (redundant per block, from partials) + per-pixel minmax (f4).
__global__ __launch_bounds__(256) void k_minmax(const f4* __restrict__ in4,
                                                float* __restrict__ ws) {
    __shared__ float vsh[14];
    __shared__ float Msh[36];
    const int b = blockIdx.y, bx = blockIdx.x, tid = threadIdx.x;
    if (tid < 14) {
        const float* part = ws + 512 + (size_t)b * NBLKV * 16 + tid;
        float s = 0.f;
#pragma unroll 5
        for (int blk = 0; blk < NBLKV; blk++) s += part[blk * 16];
        vsh[tid] = s;
    }
    __syncthreads();
    if (tid < 3) {
        int k = tid;
        float lp0 = 0, lp1 = 0, lp2 = 0, rp0 = 0, rp1 = 0, rp2 = 0;
        if (k > 0) {
            const float* v = vsh + (k - 1) * 7;
            float d = v[0] + 1e-5f;
            lp0 = v[1] / d; lp1 = v[2] / d; lp2 = v[3] / d;
            rp0 = v[4] / d; rp1 = v[5] / d; rp2 = v[6] / d;
        }
        float rx = -rp0, ry = -rp1, rz = -rp2;
        float ang = sqrtf(rx * rx + ry * ry + rz * rz) + 1e-8f;
        float ax = rx / ang, ay = ry / ang, az = rz / ang;
        float K[3][3] = {{0.f, -az, ay}, {az, 0.f, -ax}, {-ay, ax, 0.f}};
        float c = cosf(ang), s = sinf(ang);
        float K2[3][3], Rm[3][3];
#pragma unroll
        for (int i = 0; i < 3; i++)
#pragma unroll
            for (int j = 0; j < 3; j++)
                K2[i][j] = K[i][0] * K[0][j] + K[i][1] * K[1][j] + K[i][2] * K[2][j];
#pragma unroll
        for (int i = 0; i < 3; i++)
#pragma unroll
            for (int j = 0; j < 3; j++)
                Rm[i][j] = (i == j ? 1.f : 0.f) + s * K[i][j] + (1.f - c) * K2[i][j];
#pragma unroll
        for (int i = 0; i < 3; i++) {
            float tt = (i == 0 ? lp0 : (i == 1 ? lp1 : lp2));
            float tr = tt - (Rm[i][0] * lp0 + Rm[i][1] * lp1 + Rm[i][2] * lp2);
            Msh[k * 12 + i * 4 + 0] = Rm[i][0];
            Msh[k * 12 + i * 4 + 1] = Rm[i][1];
            Msh[k * 12 + i * 4 + 2] = Rm[i][2];
            Msh[k * 12 + i * 4 + 3] = tr;
            if (bx == 0) {
                float* M = ws + 64 + (b * 3 + k) * 12;
                M[i * 4 + 0] = Rm[i][0]; M[i * 4 + 1] = Rm[i][1];
                M[i * 4 + 2] = Rm[i][2]; M[i * 4 + 3] = tr;
            }
        }
    }
    __syncthreads();

    const size_t ib = (size_t)b * NCH * HW4 + bx * 256 + tid;
    f4 n0 = in4[ib], n1 = in4[ib + HW4], n2 = in4[ib + 2 * HW4];
    f4 mv = in4[ib + 3 * HW4];
    f4 g0 = in4[ib + 16 * HW4], g1 = in4[ib + 17 * HW4];
    f4 g2 = in4[ib + 18 * HW4], g3 = in4[ib + 19 * HW4];
    float mn[3] = {BIGF, BIGF, BIGF}, mx[3] = {-BIGF, -BIGF, -BIGF};
#pragma unroll
    for (int k = 0; k < 4; k++) {
        float m = sigmoidf_(mv[k]);
        if (!(m > THRESHF)) continue;
        int am = 0; float bb = g0[k];
        if (g1[k] > bb) { bb = g1[k]; am = 1; }
        if (g2[k] > bb) { bb = g2[k]; am = 2; }
        if (g3[k] > bb) { bb = g3[k]; am = 3; }
        float px = 0.f, py = 0.f, pz = 0.f;
        if (am > 0) {
            const float* Mk = Msh + (am - 1) * 12;
            float a = n0[k], bq = n1[k], cq = n2[k];
            px = Mk[0] * a + Mk[1] * bq + Mk[2]  * cq + Mk[3];
            py = Mk[4] * a + Mk[5] * bq + Mk[6]  * cq + Mk[7];
            pz = Mk[8] * a + Mk[9] * bq + Mk[10] * cq + Mk[11];
        }
        mn[0] = fminf(mn[0], px); mn[1] = fminf(mn[1], py); mn[2] = fminf(mn[2], pz);
        mx[0] = fmaxf(mx[0], px); mx[1] = fmaxf(mx[1], py); mx[2] = fmaxf(mx[2], pz);
    }
    __shared__ float rmn[4][3], rmx[4][3];
    int lane = tid & 63, wid = tid >> 6;
#pragma unroll
    for (int i = 0; i < 3; i++) {
        float v = mn[i];
        for (int off = 32; off > 0; off >>= 1) v = fminf(v, __shfl_down(v, off, 64));
        if (lane == 0) rmn[wid][i] = v;
        float u = mx[i];
        for (int off = 32; off > 0; off >>= 1) u = fmaxf(u, __shfl_down(u, off, 64));
        if (lane == 0) rmx[wid][i] = u;
    }
    __syncthreads();
    unsigned* keys = (unsigned*)(ws + 256);
    if (tid < 3) {
        float v = fminf(fminf(rmn[0][tid], rmn[1][tid]), fminf(rmn[2][tid], rmn[3][tid]));
        atomicMin(&keys[b * 6 + tid], fkey(v));
    } else if (tid < 6) {
        int i = tid - 3;
        float v = fmaxf(fmaxf(rmx[0][i], rmx[1][i]), fmaxf(rmx[2][i], rmx[3][i]));
        atomicMax(&keys[b * 6 + 3 + i], fkey(v));
    }
}

// ALL out_cat copies + pn + dedup'd voxel scatter + accz spec aggregation.
// R6 structure (best: 143 µs) with f4 copies, wave-dedup, and REGULAR stores
// to d_out (experiment: NT stores to d_out bypass L2 write aggregation).
template<bool VOXMAJOR>
__global__ __launch_bounds__(256) void k_scatter(const f4* __restrict__ in4,
                                                 f4* __restrict__ out4,
                                                 float* __restrict__ dst,
                                                 const float* __restrict__ ws) {
    __shared__ float tile[64][257];
    __shared__ float accz[4][64];
    const int b = blockIdx.y, blk = blockIdx.x;
    const int tid = threadIdx.x, lane = tid & 63, w = tid >> 6;
    const size_t ib4 = (size_t)b * NCH * HW4 + (size_t)blk * 64;
    const size_t ob4 = (size_t)b * OCH * HW4 + (size_t)blk * 64;

    // prep decode (uniform per thread)
    const unsigned* keys = (const unsigned*)(ws + 256);
    float l0 = funkey(keys[b * 6 + 0]), l1 = funkey(keys[b * 6 + 1]), l2 = funkey(keys[b * 6 + 2]);
    float u0 = funkey(keys[b * 6 + 3]), u1 = funkey(keys[b * 6 + 4]), u2 = funkey(keys[b * 6 + 5]);
    float scale = fmaxf(u0 - l0, fmaxf(u1 - l1, u2 - l2));
    float safe = (scale == 0.f) ? 1.f : scale;
    bool flag = scale != 0.f;
    float z0 = flag ? (0.f - l0) / safe : 0.f;
    float z1 = flag ? (0.f - l1) / safe : 0.f;
    float z2 = flag ? (0.f - l2) / safe : 0.f;
    const int fl0 = vox1(z0) * 1024 + vox1(z1) * 32 + vox1(z2);

    // per-pixel info (px = blk*256 + tid), scalar reads
    const float* ibs = (const float*)in4 + (size_t)b * NCH * HW + blk * 256 + tid;
    float* obs = (float*)out4 + (size_t)b * OCH * HW + blk * 256 + tid;
    float n0 = ibs[0], n1 = ibs[(size_t)HW], n2 = ibs[(size_t)2 * HW];
    float mvv = ibs[(size_t)3 * HW];
    float g0 = ibs[(size_t)16 * HW], g1 = ibs[(size_t)17 * HW];
    float g2 = ibs[(size_t)18 * HW], g3 = ibs[(size_t)19 * HW];
    float m = sigmoidf_(mvv);
    bool masked = m > THRESHF;
    int am = 0;
    { float bb = g0;
      if (g1 > bb) { bb = g1; am = 1; }
      if (g2 > bb) { bb = g2; am = 2; }
      if (g3 > bb) { bb = g3; am = 3; } }
    bool glb  = masked && (am != 0);
    bool spec = masked && (am == 0);
    float px = 0.f, py = 0.f, pz = 0.f;
    if (am > 0) {
        const float* Mk = ws + 64 + b * 36 + (am - 1) * 12;
        px = Mk[0] * n0 + Mk[1] * n1 + Mk[2]  * n2 + Mk[3];
        py = Mk[4] * n0 + Mk[5] * n1 + Mk[6]  * n2 + Mk[7];
        pz = Mk[8] * n0 + Mk[9] * n1 + Mk[10] * n2 + Mk[11];
    }
    float qx, qy, qz;
    if (flag) { qx = (px - l0) / safe; qy = (py - l1) / safe; qz = (pz - l2) / safe; }
    else      { qx = px; qy = py; qz = pz; }
    float ox = masked ? qx : 0.f, oy = masked ? qy : 0.f, oz = masked ? qz : 0.f;
    obs[(size_t)86 * HW] = ox;          // REGULAR stores to d_out
    obs[(size_t)87 * HW] = oy;
    obs[(size_t)88 * HW] = oz;
    int flat = glb ? (vox1(ox) * 1024 + vox1(oy) * 32 + vox1(oz)) : fl0;
    unsigned long long gm = __ballot(glb);
    unsigned long long sm = __ballot(spec);

    // phase A: copy ch 0..21, f4, REGULAR load + REGULAR store
#pragma unroll
    for (int i = 0; i < 6; i++) {
        int c = w + 4 * i;
        if (c < 22) {
            f4 v = in4[ib4 + (size_t)c * HW4 + lane];
            out4[ob4 + (size_t)c * HW4 + lane] = v;
        }
    }
    // feat ch 22..85: f4 copy + LDS stage (wave w: 16 channels)
#pragma unroll
    for (int i = 0; i < 16; i++) {
        int c = w * 16 + i;
        f4 v = in4[ib4 + (size_t)(22 + c) * HW4 + lane];
        out4[ob4 + (size_t)(22 + c) * HW4 + lane] = v;
        tile[c][4 * lane + 0] = v[0]; tile[c][4 * lane + 1] = v[1];
        tile[c][4 * lane + 2] = v[2]; tile[c][4 * lane + 3] = v[3];
    }
    __syncthreads();   // tile ready

    // dedup'd drain for glb voxels: one 256B wave-atomic per DISTINCT voxel
    while (gm) {
        int i0 = __ffsll(gm) - 1;
        int fl = __shfl(flat, i0, 64);
        unsigned long long match = __ballot(flat == fl) & gm;
        gm &= ~match;
        float s = 0.f;
        unsigned long long mm = match;
        while (mm) {
            int j = __ffsll(mm) - 1; mm &= mm - 1;
            s += tile[lane][w * 64 + j];
        }
        if (VOXMAJOR)
            atomicAdd(&dst[(((size_t)b * VOX + fl) << 6) + lane], s);
        else
            atomicAdd(&dst[(((size_t)(b * 64 + lane)) << 15) + fl], s);
    }
    // spec pixels (shared voxel fl0): block-level aggregation, 1 atomic/block
    float sacc = 0.f;
    while (sm) {
        int j = __ffsll(sm) - 1; sm &= sm - 1;
        sacc += tile[lane][w * 64 + j];
    }
    accz[w][lane] = sacc;
    __syncthreads();
    if (tid < 64) {
        float s = accz[0][tid] + accz[1][tid] + accz[2][tid] + accz[3][tid];
        if (s != 0.f) {
            if (VOXMAJOR)
                atomicAdd(&dst[(((size_t)b * VOX + fl0) << 6) + tid], s);
            else
                atomicAdd(&dst[(((size_t)(b * 64 + tid)) << 15) + fl0], s);
        }
    }
}

// tmp[b][vox][64] -> occ[b][64][vox], 64-voxel tiles, REGULAR stores to d_out.
__global__ __launch_bounds__(256) void k_transpose(const float* __restrict__ tmp,
                                                   float* __restrict__ occ) {
    __shared__ float ld[64][65];
    const int b = blockIdx.y;
    const int vox0 = blockIdx.x * 64;
    const int t = threadIdx.x;
    const int v = t & 63, g = t >> 6;
    const float* src = tmp + (((size_t)b * VOX + vox0 + v) << 6) + g * 16;
#pragma unroll
    for (int i = 0; i < 4; i++) {
        f4 x = *(const f4*)(src + 4 * i);
        ld[g * 16 + 4 * i + 0][v] = x[0];
        ld[g * 16 + 4 * i + 1][v] = x[1];
        ld[g * 16 + 4 * i + 2][v] = x[2];
        ld[g * 16 + 4 * i + 3][v] = x[3];
    }
    __syncthreads();
    const int f = t >> 2;
    float* dstp = occ + (((size_t)(b * 64 + f)) << 15) + vox0;
#pragma unroll
    for (int i = 0; i < 4; i++) {
        int mq = (t & 3) * 4 + i;
        f4 x;
        x[0] = ld[f][4 * mq + 0]; x[1] = ld[f][4 * mq + 1];
        x[2] = ld[f][4 * mq + 2]; x[3] = ld[f][4 * mq + 3];
        *(f4*)(dstp + 4 * mq) = x;
    }
}

extern "C" void kernel_launch(void* const* d_in, const int* in_sizes, int n_in,
                              void* d_out, int out_size, void* d_ws, size_t ws_size,
                              hipStream_t stream) {
    const f4* in4 = (const f4*)d_in[0];
    float* out = (float*)d_out;
    float* ws = (float*)d_ws;
    float* occ = out + (size_t)NB * OCH * HW;
    float* tmp = ws + 32768;
    const size_t tmp_bytes = (size_t)NB * VOX * 64 * sizeof(float);
    const bool voxmajor = ws_size >= 32768 * sizeof(float) + tmp_bytes;
    const unsigned n4 = (unsigned)(tmp_bytes / 16);

    dim3 g75(NBLKV, NB);
    if (voxmajor) k_votes_zero<<<g75, 256, 0, stream>>>(in4, ws, (f4*)tmp, n4);
    else          k_votes_zero<<<g75, 256, 0, stream>>>(in4, ws, (f4*)occ, n4);
    k_minmax<<<g75, 256, 0, stream>>>(in4, ws);
    dim3 gs(300, NB);
    if (voxmajor) {
        k_scatter<true><<<gs, 256, 0, stream>>>(in4, (f4*)out, tmp, ws);
        dim3 gt(VOX / 64, NB);
        k_transpose<<<gt, 256, 0, stream>>>(tmp, occ);
    } else {
        k_scatter<false><<<gs, 256, 0, stream>>>(in4, (f4*)out, occ, ws);
    }
}

// Round 12
// 100.813 us; speedup vs baseline: 1.8949x; 1.0253x over previous
//
#include <hip/hip_runtime.h>
#include <math.h>

#define HW     76800
#define HW4    19200
#define NCH    86
#define OCH    89
#define NB     4
#define VOX    32768
#define NBLKV  75         // f4 blocks per batch (1024 px each)
#define THRESHF 0.7f
#define BIGF   1e30f

typedef float f4 __attribute__((ext_vector_type(4)));

// ws float layout:
// [64..207]   M: (b*3 + k)*12 row-major 3x4 [R|t]     (written by k_minmax bx==0)
// [256..279]  minmax keys (uint32): b*6 + c           (init by k_votes_zero)
// [512..5312) vote partials: (b*75+bx)*16 + i, i<14   (k_votes_zero)
// [8192..12288) dirty bitmap: (unsigned*)(ws+8192), b*1024 words (VOX bits/batch)
// [32768..]   occ_tmp: [b][vox][64] voxel-major scratch (33.5 MB)

__device__ __forceinline__ float sigmoidf_(float x) {
    if (x >= 0.f) { return 1.f / (1.f + expf(-x)); }
    float e = expf(x); return e / (1.f + e);
}
__device__ __forceinline__ unsigned fkey(float f) {
    unsigned u = __float_as_uint(f);
    return (u & 0x80000000u) ? ~u : (u | 0x80000000u);
}
__device__ __forceinline__ float funkey(unsigned k) {
    unsigned u = (k & 0x80000000u) ? (k ^ 0x80000000u) : ~k;
    return __uint_as_float(u);
}
__device__ __forceinline__ int vox1(float q) {
    int v = (int)floorf(q * 32.f);
    return v < 0 ? 0 : (v > 31 ? 31 : v);
}

// grid (150, NB): bx<75 -> votes; bx>=75 -> zero tmp slice + bitmap + keys.
// Split so the 33.5MB zero and the 18MB vote reads run on DIFFERENT CUs
// concurrently instead of serializing inside each block.
__global__ __launch_bounds__(256) void k_votes_zero(const f4* __restrict__ in4,
                                                    float* __restrict__ ws,
                                                    f4* __restrict__ zp, unsigned n4) {
    const int b = blockIdx.y, bx = blockIdx.x;
    const int tid = threadIdx.x;

    if (bx >= NBLKV) {   // zero-only block
        const int zb = b * NBLKV + (bx - NBLKV);        // 0..299
        unsigned gid = (unsigned)zb * 256u + tid;
        f4 z = {0.f, 0.f, 0.f, 0.f};
        for (unsigned i = gid; i < n4; i += NB * NBLKV * 256u)
            __builtin_nontemporal_store(z, &zp[i]);     // d_ws: NT is fast
        if (gid < NB * 1024) ((unsigned*)(ws + 8192))[gid] = 0u;   // bitmap
        if (zb == 0 && tid < 24) {
            unsigned* keys = (unsigned*)(ws + 256);
            keys[tid] = ((tid % 6) < 3) ? fkey(BIGF) : fkey(-BIGF);
        }
        return;
    }

    const size_t ib = (size_t)b * NCH * HW4 + bx * 256 + tid;
    f4 mv = in4[ib + (size_t)3 * HW4];
    f4 c0 = in4[ib + (size_t)20 * HW4];
    f4 c1 = in4[ib + (size_t)21 * HW4];
    f4 L[12];
#pragma unroll
    for (int i = 0; i < 12; i++) L[i] = in4[ib + (size_t)(4 + i) * HW4];
    float acc[14];
#pragma unroll
    for (int i = 0; i < 14; i++) acc[i] = 0.f;
#pragma unroll
    for (int k = 0; k < 4; k++) {
        float m  = sigmoidf_(mv[k]);
        float s0 = sigmoidf_(c0[k]) * m;
        float s1 = sigmoidf_(c1[k]) * m;
        float w0 = m * s0, w1 = m * s1;
        acc[0] += s0; acc[7] += s1;
#pragma unroll
        for (int c = 0; c < 3; c++) {
            acc[1 + c]  += L[c][k]     * w0;
            acc[8 + c]  += L[3 + c][k] * w1;
            acc[4 + c]  += L[6 + c][k] * w0;
            acc[11 + c] += L[9 + c][k] * w1;
        }
    }
    __shared__ float red[4][14];
    int lane = tid & 63, wid = tid >> 6;
#pragma unroll
    for (int i = 0; i < 14; i++) {
        float v = acc[i];
        for (int off = 32; off > 0; off >>= 1) v += __shfl_down(v, off, 64);
        if (lane == 0) red[wid][i] = v;
    }
    __syncthreads();
    if (tid < 14)
        ws[512 + (b * NBLKV + bx) * 16 + tid] =
            red[0][tid] + red[1][tid] + red[2][tid] + red[3][tid];
}

// build M (redundant per block, from partials) + per-pixel minmax (f4).
__global__ __launch_bounds__(256) void k_minmax(const f4* __restrict__ in4,
                                                float* __restrict__ ws) {
    __shared__ float vsh[14];
    __shared__ float Msh[36];
    const int b = blockIdx.y, bx = blockIdx.x, tid = threadIdx.x;
    if (tid < 14) {
        const float* part = ws + 512 + (size_t)b * NBLKV * 16 + tid;
        float s = 0.f;
#pragma unroll 5
        for (int blk = 0; blk < NBLKV; blk++) s += part[blk * 16];
        vsh[tid] = s;
    }
    __syncthreads();
    if (tid < 3) {
        int k = tid;
        float lp0 = 0, lp1 = 0, lp2 = 0, rp0 = 0, rp1 = 0, rp2 = 0;
        if (k > 0) {
            const float* v = vsh + (k - 1) * 7;
            float d = v[0] + 1e-5f;
            lp0 = v[1] / d; lp1 = v[2] / d; lp2 = v[3] / d;
            rp0 = v[4] / d; rp1 = v[5] / d; rp2 = v[6] / d;
        }
        float rx = -rp0, ry = -rp1, rz = -rp2;
        float ang = sqrtf(rx * rx + ry * ry + rz * rz) + 1e-8f;
        float ax = rx / ang, ay = ry / ang, az = rz / ang;
        float K[3][3] = {{0.f, -az, ay}, {az, 0.f, -ax}, {-ay, ax, 0.f}};
        float c = cosf(ang), s = sinf(ang);
        float K2[3][3], Rm[3][3];
#pragma unroll
        for (int i = 0; i < 3; i++)
#pragma unroll
            for (int j = 0; j < 3; j++)
                K2[i][j] = K[i][0] * K[0][j] + K[i][1] * K[1][j] + K[i][2] * K[2][j];
#pragma unroll
        for (int i = 0; i < 3; i++)
#pragma unroll
            for (int j = 0; j < 3; j++)
                Rm[i][j] = (i == j ? 1.f : 0.f) + s * K[i][j] + (1.f - c) * K2[i][j];
#pragma unroll
        for (int i = 0; i < 3; i++) {
            float tt = (i == 0 ? lp0 : (i == 1 ? lp1 : lp2));
            float tr = tt - (Rm[i][0] * lp0 + Rm[i][1] * lp1 + Rm[i][2] * lp2);
            Msh[k * 12 + i * 4 + 0] = Rm[i][0];
            Msh[k * 12 + i * 4 + 1] = Rm[i][1];
            Msh[k * 12 + i * 4 + 2] = Rm[i][2];
            Msh[k * 12 + i * 4 + 3] = tr;
            if (bx == 0) {
                float* M = ws + 64 + (b * 3 + k) * 12;
                M[i * 4 + 0] = Rm[i][0]; M[i * 4 + 1] = Rm[i][1];
                M[i * 4 + 2] = Rm[i][2]; M[i * 4 + 3] = tr;
            }
        }
    }
    __syncthreads();

    const size_t ib = (size_t)b * NCH * HW4 + bx * 256 + tid;
    f4 n0 = in4[ib], n1 = in4[ib + HW4], n2 = in4[ib + 2 * HW4];
    f4 mv = in4[ib + 3 * HW4];
    f4 g0 = in4[ib + 16 * HW4], g1 = in4[ib + 17 * HW4];
    f4 g2 = in4[ib + 18 * HW4], g3 = in4[ib + 19 * HW4];
    float mn[3] = {BIGF, BIGF, BIGF}, mx[3] = {-BIGF, -BIGF, -BIGF};
#pragma unroll
    for (int k = 0; k < 4; k++) {
        float m = sigmoidf_(mv[k]);
        if (!(m > THRESHF)) continue;
        int am = 0; float bb = g0[k];
        if (g1[k] > bb) { bb = g1[k]; am = 1; }
        if (g2[k] > bb) { bb = g2[k]; am = 2; }
        if (g3[k] > bb) { bb = g3[k]; am = 3; }
        float px = 0.f, py = 0.f, pz = 0.f;
        if (am > 0) {
            const float* Mk = Msh + (am - 1) * 12;
            float a = n0[k], bq = n1[k], cq = n2[k];
            px = Mk[0] * a + Mk[1] * bq + Mk[2]  * cq + Mk[3];
            py = Mk[4] * a + Mk[5] * bq + Mk[6]  * cq + Mk[7];
            pz = Mk[8] * a + Mk[9] * bq + Mk[10] * cq + Mk[11];
        }
        mn[0] = fminf(mn[0], px); mn[1] = fminf(mn[1], py); mn[2] = fminf(mn[2], pz);
        mx[0] = fmaxf(mx[0], px); mx[1] = fmaxf(mx[1], py); mx[2] = fmaxf(mx[2], pz);
    }
    __shared__ float rmn[4][3], rmx[4][3];
    int lane = tid & 63, wid = tid >> 6;
#pragma unroll
    for (int i = 0; i < 3; i++) {
        float v = mn[i];
        for (int off = 32; off > 0; off >>= 1) v = fminf(v, __shfl_down(v, off, 64));
        if (lane == 0) rmn[wid][i] = v;
        float u = mx[i];
        for (int off = 32; off > 0; off >>= 1) u = fmaxf(u, __shfl_down(u, off, 64));
        if (lane == 0) rmx[wid][i] = u;
    }
    __syncthreads();
    unsigned* keys = (unsigned*)(ws + 256);
    if (tid < 3) {
        float v = fminf(fminf(rmn[0][tid], rmn[1][tid]), fminf(rmn[2][tid], rmn[3][tid]));
        atomicMin(&keys[b * 6 + tid], fkey(v));
    } else if (tid < 6) {
        int i = tid - 3;
        float v = fmaxf(fmaxf(rmx[0][i], rmx[1][i]), fmaxf(rmx[2][i], rmx[3][i]));
        atomicMax(&keys[b * 6 + 3 + i], fkey(v));
    }
}

// ALL out_cat copies + pn + dedup'd voxel scatter + accz spec aggregation.
// Regular (non-NT) stores to d_out throughout — NT stores to d_out bypass L2
// write aggregation and run ~5x slower (R10->R11: 172->103 µs).
template<bool VOXMAJOR>
__global__ __launch_bounds__(256) void k_scatter(const f4* __restrict__ in4,
                                                 f4* __restrict__ out4,
                                                 float* __restrict__ dst,
                                                 float* __restrict__ ws) {
    __shared__ float tile[64][257];
    __shared__ float accz[4][64];
    const int b = blockIdx.y, blk = blockIdx.x;
    const int tid = threadIdx.x, lane = tid & 63, w = tid >> 6;
    const size_t ib4 = (size_t)b * NCH * HW4 + (size_t)blk * 64;
    const size_t ob4 = (size_t)b * OCH * HW4 + (size_t)blk * 64;
    unsigned* bm = (unsigned*)(ws + 8192) + b * 1024;

    // prep decode (uniform per thread)
    const unsigned* keys = (const unsigned*)(ws + 256);
    float l0 = funkey(keys[b * 6 + 0]), l1 = funkey(keys[b * 6 + 1]), l2 = funkey(keys[b * 6 + 2]);
    float u0 = funkey(keys[b * 6 + 3]), u1 = funkey(keys[b * 6 + 4]), u2 = funkey(keys[b * 6 + 5]);
    float scale = fmaxf(u0 - l0, fmaxf(u1 - l1, u2 - l2));
    float safe = (scale == 0.f) ? 1.f : scale;
    bool flag = scale != 0.f;
    float z0 = flag ? (0.f - l0) / safe : 0.f;
    float z1 = flag ? (0.f - l1) / safe : 0.f;
    float z2 = flag ? (0.f - l2) / safe : 0.f;
    const int fl0 = vox1(z0) * 1024 + vox1(z1) * 32 + vox1(z2);

    // per-pixel info (px = blk*256 + tid), scalar reads
    const float* ibs = (const float*)in4 + (size_t)b * NCH * HW + blk * 256 + tid;
    float* obs = (float*)out4 + (size_t)b * OCH * HW + blk * 256 + tid;
    float n0 = ibs[0], n1 = ibs[(size_t)HW], n2 = ibs[(size_t)2 * HW];
    float mvv = ibs[(size_t)3 * HW];
    float g0 = ibs[(size_t)16 * HW], g1 = ibs[(size_t)17 * HW];
    float g2 = ibs[(size_t)18 * HW], g3 = ibs[(size_t)19 * HW];
    float m = sigmoidf_(mvv);
    bool masked = m > THRESHF;
    int am = 0;
    { float bb = g0;
      if (g1 > bb) { bb = g1; am = 1; }
      if (g2 > bb) { bb = g2; am = 2; }
      if (g3 > bb) { bb = g3; am = 3; } }
    bool glb  = masked && (am != 0);
    bool spec = masked && (am == 0);
    float px = 0.f, py = 0.f, pz = 0.f;
    if (am > 0) {
        const float* Mk = ws + 64 + b * 36 + (am - 1) * 12;
        px = Mk[0] * n0 + Mk[1] * n1 + Mk[2]  * n2 + Mk[3];
        py = Mk[4] * n0 + Mk[5] * n1 + Mk[6]  * n2 + Mk[7];
        pz = Mk[8] * n0 + Mk[9] * n1 + Mk[10] * n2 + Mk[11];
    }
    float qx, qy, qz;
    if (flag) { qx = (px - l0) / safe; qy = (py - l1) / safe; qz = (pz - l2) / safe; }
    else      { qx = px; qy = py; qz = pz; }
    float ox = masked ? qx : 0.f, oy = masked ? qy : 0.f, oz = masked ? qz : 0.f;
    obs[(size_t)86 * HW] = ox;
    obs[(size_t)87 * HW] = oy;
    obs[(size_t)88 * HW] = oz;
    int flat = glb ? (vox1(ox) * 1024 + vox1(oy) * 32 + vox1(oz)) : fl0;
    unsigned long long gm = __ballot(glb);
    unsigned long long sm = __ballot(spec);

    // phase A: copy ch 0..21, f4 (regular loads keep lines hot for re-reads)
#pragma unroll
    for (int i = 0; i < 6; i++) {
        int c = w + 4 * i;
        if (c < 22) {
            f4 v = in4[ib4 + (size_t)c * HW4 + lane];
            out4[ob4 + (size_t)c * HW4 + lane] = v;
        }
    }
    // feat ch 22..85: f4 copy + LDS stage (wave w: 16 channels)
#pragma unroll
    for (int i = 0; i < 16; i++) {
        int c = w * 16 + i;
        f4 v = in4[ib4 + (size_t)(22 + c) * HW4 + lane];
        out4[ob4 + (size_t)(22 + c) * HW4 + lane] = v;
        tile[c][4 * lane + 0] = v[0]; tile[c][4 * lane + 1] = v[1];
        tile[c][4 * lane + 2] = v[2]; tile[c][4 * lane + 3] = v[3];
    }
    if (VOXMAJOR && tid == 0 && sm)           // spec voxel will be dirtied
        atomicOr(&bm[fl0 >> 5], 1u << (fl0 & 31));
    __syncthreads();   // tile ready

    // dedup'd drain: one 256B wave-atomic per DISTINCT voxel (+dirty bit)
    while (gm) {
        int i0 = __ffsll(gm) - 1;
        int fl = __shfl(flat, i0, 64);
        unsigned long long match = __ballot(flat == fl) & gm;
        gm &= ~match;
        float s = 0.f;
        unsigned long long mm = match;
        while (mm) {
            int j = __ffsll(mm) - 1; mm &= mm - 1;
            s += tile[lane][w * 64 + j];
        }
        if (VOXMAJOR) {
            if (lane == 0) atomicOr(&bm[fl >> 5], 1u << (fl & 31));
            atomicAdd(&dst[(((size_t)b * VOX + fl) << 6) + lane], s);
        } else {
            atomicAdd(&dst[(((size_t)(b * 64 + lane)) << 15) + fl], s);
        }
    }
    // spec pixels (shared voxel fl0): block-level aggregation, 1 atomic/block
    float sacc = 0.f;
    while (sm) {
        int j = __ffsll(sm) - 1; sm &= sm - 1;
        sacc += tile[lane][w * 64 + j];
    }
    accz[w][lane] = sacc;
    __syncthreads();
    if (tid < 64) {
        float s = accz[0][tid] + accz[1][tid] + accz[2][tid] + accz[3][tid];
        if (s != 0.f) {
            if (VOXMAJOR)
                atomicAdd(&dst[(((size_t)b * VOX + fl0) << 6) + tid], s);
            else
                atomicAdd(&dst[(((size_t)(b * 64 + tid)) << 15) + fl0], s);
        }
    }
}

// tmp[b][vox][64] -> occ[b][64][vox], 64-voxel tiles. Dirty-bitmap skip:
// clean voxel groups write zeros without reading tmp (saves most of 33.5MB).
__global__ __launch_bounds__(256) void k_transpose(const float* __restrict__ tmp,
                                                   float* __restrict__ occ,
                                                   const float* __restrict__ ws) {
    __shared__ float ld[64][65];
    const int b = blockIdx.y;
    const int vox0 = blockIdx.x * 64;
    const int t = threadIdx.x;
    const unsigned* bm = (const unsigned*)(ws + 8192) + b * 1024;
    const unsigned dirty = bm[vox0 >> 5] | bm[(vox0 >> 5) + 1];
    const int f = t >> 2, sub = t & 3;
    float* dstp = occ + (((size_t)(b * 64 + f)) << 15) + vox0;

    if (dirty == 0u) {   // whole 64-voxel group untouched -> zeros
        f4 z = {0.f, 0.f, 0.f, 0.f};
#pragma unroll
        for (int i = 0; i < 4; i++)
            *(f4*)(dstp + 4 * (sub * 4 + i)) = z;
        return;
    }
    const int v = t & 63, g = t >> 6;
    const float* src = tmp + (((size_t)b * VOX + vox0 + v) << 6) + g * 16;
#pragma unroll
    for (int i = 0; i < 4; i++) {
        f4 x = *(const f4*)(src + 4 * i);
        ld[g * 16 + 4 * i + 0][v] = x[0];
        ld[g * 16 + 4 * i + 1][v] = x[1];
        ld[g * 16 + 4 * i + 2][v] = x[2];
        ld[g * 16 + 4 * i + 3][v] = x[3];
    }
    __syncthreads();
#pragma unroll
    for (int i = 0; i < 4; i++) {
        int mq = sub * 4 + i;
        f4 x;
        x[0] = ld[f][4 * mq + 0]; x[1] = ld[f][4 * mq + 1];
        x[2] = ld[f][4 * mq + 2]; x[3] = ld[f][4 * mq + 3];
        *(f4*)(dstp + 4 * mq) = x;
    }
}

extern "C" void kernel_launch(void* const* d_in, const int* in_sizes, int n_in,
                              void* d_out, int out_size, void* d_ws, size_t ws_size,
                              hipStream_t stream) {
    const f4* in4 = (const f4*)d_in[0];
    float* out = (float*)d_out;
    float* ws = (float*)d_ws;
    float* occ = out + (size_t)NB * OCH * HW;
    float* tmp = ws + 32768;
    const size_t tmp_bytes = (size_t)NB * VOX * 64 * sizeof(float);
    const bool voxmajor = ws_size >= 32768 * sizeof(float) + tmp_bytes;
    const unsigned n4 = (unsigned)(tmp_bytes / 16);

    dim3 gv(NBLKV * 2, NB);
    if (voxmajor) k_votes_zero<<<gv, 256, 0, stream>>>(in4, ws, (f4*)tmp, n4);
    else          k_votes_zero<<<gv, 256, 0, stream>>>(in4, ws, (f4*)occ, n4);
    dim3 g75(NBLKV, NB);
    k_minmax<<<g75, 256, 0, stream>>>(in4, ws);
    dim3 gs(300, NB);
    if (voxmajor) {
        k_scatter<true><<<gs, 256, 0, stream>>>(in4, (f4*)out, tmp, ws);
        dim3 gt(VOX / 64, NB);
        k_transpose<<<gt, 256, 0, stream>>>(tmp, occ, ws);
    } else {
        k_scatter<false><<<gs, 256, 0, stream>>>(in4, (f4*)out, occ, ws);
    }
}